// Round 8
// baseline (2613.169 us; speedup 1.0000x reference)
//
#include <hip/hip_runtime.h>
#include <cmath>

// Problem constants
#define Bb   64
#define Tt   128
#define Dd   2048
#define Hh   512
#define Gg   2048      // 4*H
#define Cc   101
#define ROWS 8192      // B*T

typedef unsigned short u16;
typedef __attribute__((ext_vector_type(8))) short bf16x8;
typedef __attribute__((ext_vector_type(4))) float f32x4;

// ---------------- bf16 hi/lo split helpers ----------------
__device__ __forceinline__ u16 bf16rne(float x) {
  unsigned u = __float_as_uint(x);
  unsigned r = (u + 0x7fffu + ((u >> 16) & 1u)) >> 16;
  return (u16)r;
}
__device__ __forceinline__ void split_bf16(float x, u16& h, u16& l) {
  h = bf16rne(x);
  l = bf16rne(x - __uint_as_float(((unsigned)h) << 16));
}
__device__ __forceinline__ float sigm(float x) { return 1.f / (1.f + expf(-x)); }

// X [ROWS x Dd] fp32 -> Xhi, Xlo bf16 (same layout)
__global__ __launch_bounds__(256)
void convert_hilo(const float* __restrict__ src, u16* __restrict__ hi,
                  u16* __restrict__ lo, int n4) {
  for (int i = blockIdx.x * 256 + threadIdx.x; i < n4; i += gridDim.x * 256) {
    const float4 v = ((const float4*)src)[i];
    ushort4 h, l;
    split_bf16(v.x, h.x, l.x);
    split_bf16(v.y, h.y, l.y);
    split_bf16(v.z, h.z, l.z);
    split_bf16(v.w, h.w, l.w);
    ((ushort4*)hi)[i] = h;
    ((ushort4*)lo)[i] = l;
  }
}

// W1 top [Dd x Gg] -> W1T hi/lo [Gg x Dd] bf16  (for gemm1 B operand)
__global__ __launch_bounds__(256)
void convertT_w1(const float* __restrict__ W1, u16* __restrict__ Th,
                 u16* __restrict__ Tl) {
  __shared__ float tl[32][33];
  const int tx = threadIdx.x, ty = threadIdx.y;   // 32, 8
  const int k0 = blockIdx.x * 32, c0 = blockIdx.y * 32;
#pragma unroll
  for (int j = 0; j < 4; ++j)
    tl[ty + j * 8][tx] = W1[(size_t)(k0 + ty + j * 8) * Gg + (c0 + tx)];
  __syncthreads();
#pragma unroll
  for (int j = 0; j < 4; ++j) {
    const float v = tl[tx][ty + j * 8];
    u16 h, l;
    split_bf16(v, h, l);
    const size_t o = (size_t)(c0 + ty + j * 8) * Dd + (k0 + tx);
    Th[o] = h;
    Tl[o] = l;
  }
}

// Recurrent weights, permuted + split:
// WP[cg 128][vc 16][K], vc = g*4 + m for col = g*512 + cg*4 + m.
__global__ __launch_bounds__(256)
void permuteW(const float* __restrict__ src, u16* __restrict__ dh,
              u16* __restrict__ dl, int K) {
  __shared__ float tl[32][33];
  const int tx = threadIdx.x, ty = threadIdx.y;   // 32, 8
  const int k0 = blockIdx.x * 32, c0 = blockIdx.y * 32;
#pragma unroll
  for (int j = 0; j < 4; ++j)
    tl[ty + j * 8][tx] = src[(size_t)(k0 + ty + j * 8) * Gg + (c0 + tx)];
  __syncthreads();
#pragma unroll
  for (int j = 0; j < 4; ++j) {
    const int col = c0 + ty + j * 8;
    const int g = col >> 9, mg = col & 511;
    const int cg = mg >> 2, m = mg & 3;
    const float v = tl[tx][ty + j * 8];
    u16 h, l;
    split_bf16(v, h, l);
    const size_t o = (size_t)(cg * 16 + g * 4 + m) * K + k0 + tx;
    dh[o] = h;
    dl[o] = l;
  }
}

// ---------------- MFMA bf16x3 GEMM: pre = X @ W1 + b1 ----------------
__global__ __launch_bounds__(256)
void gemm1_mfma(const u16* __restrict__ Ah, const u16* __restrict__ Al,
                const u16* __restrict__ Bh, const u16* __restrict__ Bl,
                const float* __restrict__ bias, float* __restrict__ C) {
  __shared__ u16 Ash[128][40];
  __shared__ u16 Asl[128][40];
  __shared__ u16 Bsh[128][40];
  __shared__ u16 Bsl[128][40];
  const int tid  = threadIdx.x;
  const int lane = tid & 63, wave = tid >> 6;
  const int wm = wave >> 1, wn = wave & 1;
  const int l15 = lane & 15, k8 = (lane >> 4) * 8, r4 = (lane >> 4) * 4;
  const int row0 = blockIdx.y * 128, col0 = blockIdx.x * 128;
  const int srow = tid >> 1, sk = (tid & 1) * 16;

  const u16* pAh = Ah + (size_t)(row0 + srow) * Dd + sk;
  const u16* pAl = Al + (size_t)(row0 + srow) * Dd + sk;
  const u16* pBh = Bh + (size_t)(col0 + srow) * Dd + sk;
  const u16* pBl = Bl + (size_t)(col0 + srow) * Dd + sk;

  f32x4 acc[4][4];
#pragma unroll
  for (int i = 0; i < 4; ++i)
#pragma unroll
    for (int j = 0; j < 4; ++j) acc[i][j] = (f32x4){0.f, 0.f, 0.f, 0.f};

  for (int k0 = 0; k0 < Dd; k0 += 32) {
    *(bf16x8*)(&Ash[srow][sk])     = *(const bf16x8*)(pAh + k0);
    *(bf16x8*)(&Ash[srow][sk + 8]) = *(const bf16x8*)(pAh + k0 + 8);
    *(bf16x8*)(&Asl[srow][sk])     = *(const bf16x8*)(pAl + k0);
    *(bf16x8*)(&Asl[srow][sk + 8]) = *(const bf16x8*)(pAl + k0 + 8);
    *(bf16x8*)(&Bsh[srow][sk])     = *(const bf16x8*)(pBh + k0);
    *(bf16x8*)(&Bsh[srow][sk + 8]) = *(const bf16x8*)(pBh + k0 + 8);
    *(bf16x8*)(&Bsl[srow][sk])     = *(const bf16x8*)(pBl + k0);
    *(bf16x8*)(&Bsl[srow][sk + 8]) = *(const bf16x8*)(pBl + k0 + 8);
    __syncthreads();

    bf16x8 afh[4], afl[4], bfh[4], bfl[4];
#pragma unroll
    for (int mt = 0; mt < 4; ++mt) {
      afh[mt] = *(const bf16x8*)(&Ash[wm * 64 + mt * 16 + l15][k8]);
      afl[mt] = *(const bf16x8*)(&Asl[wm * 64 + mt * 16 + l15][k8]);
    }
#pragma unroll
    for (int nt = 0; nt < 4; ++nt) {
      bfh[nt] = *(const bf16x8*)(&Bsh[wn * 64 + nt * 16 + l15][k8]);
      bfl[nt] = *(const bf16x8*)(&Bsl[wn * 64 + nt * 16 + l15][k8]);
    }
#pragma unroll
    for (int mt = 0; mt < 4; ++mt)
#pragma unroll
      for (int nt = 0; nt < 4; ++nt) {
        acc[mt][nt] = __builtin_amdgcn_mfma_f32_16x16x32_bf16(
            afh[mt], bfh[nt], acc[mt][nt], 0, 0, 0);
        acc[mt][nt] = __builtin_amdgcn_mfma_f32_16x16x32_bf16(
            afh[mt], bfl[nt], acc[mt][nt], 0, 0, 0);
        acc[mt][nt] = __builtin_amdgcn_mfma_f32_16x16x32_bf16(
            afl[mt], bfh[nt], acc[mt][nt], 0, 0, 0);
      }
    __syncthreads();
  }

#pragma unroll
  for (int nt = 0; nt < 4; ++nt) {
    const int col = col0 + wn * 64 + nt * 16 + l15;
    const float bj = bias[col];
#pragma unroll
    for (int mt = 0; mt < 4; ++mt) {
      float* Cp = C + (size_t)(row0 + wm * 64 + mt * 16 + r4) * Gg + col;
#pragma unroll
      for (int r = 0; r < 4; ++r)
        Cp[(size_t)r * Gg] = acc[mt][nt][r] + bj;
    }
  }
}

// ---------------- SGEMM (fp32 fallback if ws too small) ----------------
#define BM 128
#define BN 128
#define BK 16

__global__ __launch_bounds__(256)
void sgemm_bias(const float* __restrict__ A, const float* __restrict__ B,
                const float* __restrict__ bias, float* __restrict__ C,
                int M, int N, int K) {
  __shared__ float As[BK][BM];
  __shared__ float Bs[BK][BN];
  const int tid  = threadIdx.x;
  const int row0 = blockIdx.y * BM, col0 = blockIdx.x * BN;
  const int tr = (tid >> 4) << 3;
  const int tc = (tid & 15) << 3;

  float acc[8][8];
#pragma unroll
  for (int i = 0; i < 8; ++i)
#pragma unroll
    for (int j = 0; j < 8; ++j) acc[i][j] = 0.f;

  const int arow = tid >> 1;
  const int acol = (tid & 1) << 3;
  const int brow = tid >> 4;
  const int bcol = (tid & 15) << 3;
  const float* Ap = A + (size_t)(row0 + arow) * K + acol;
  const float* Bp = B + (size_t)brow * N + (col0 + bcol);

  for (int k0 = 0; k0 < K; k0 += BK) {
    const float4 a0 = *(const float4*)(Ap + k0);
    const float4 a1 = *(const float4*)(Ap + k0 + 4);
    const float4 bv0 = *(const float4*)(Bp + (size_t)k0 * N);
    const float4 bv1 = *(const float4*)(Bp + (size_t)k0 * N + 4);
    As[acol + 0][arow] = a0.x;
    As[acol + 1][arow] = a0.y;
    As[acol + 2][arow] = a0.z;
    As[acol + 3][arow] = a0.w;
    As[acol + 4][arow] = a1.x;
    As[acol + 5][arow] = a1.y;
    As[acol + 6][arow] = a1.z;
    As[acol + 7][arow] = a1.w;
    *(float4*)(&Bs[brow][bcol])     = bv0;
    *(float4*)(&Bs[brow][bcol + 4]) = bv1;
    __syncthreads();
#pragma unroll
    for (int k = 0; k < BK; ++k) {
      float a[8], b[8];
      *(float4*)(a)     = *(const float4*)(&As[k][tr]);
      *(float4*)(a + 4) = *(const float4*)(&As[k][tr + 4]);
      *(float4*)(b)     = *(const float4*)(&Bs[k][tc]);
      *(float4*)(b + 4) = *(const float4*)(&Bs[k][tc + 4]);
#pragma unroll
      for (int i = 0; i < 8; ++i)
#pragma unroll
        for (int j = 0; j < 8; ++j)
          acc[i][j] = fmaf(a[i], b[j], acc[i][j]);
    }
    __syncthreads();
  }

  float bj[8];
#pragma unroll
  for (int j = 0; j < 8; ++j) bj[j] = bias[col0 + tc + j];
#pragma unroll
  for (int i = 0; i < 8; ++i) {
    float* Cp = C + (size_t)(row0 + tr + i) * N + (col0 + tc);
    float4 o0, o1;
    o0.x = acc[i][0] + bj[0]; o0.y = acc[i][1] + bj[1];
    o0.z = acc[i][2] + bj[2]; o0.w = acc[i][3] + bj[3];
    o1.x = acc[i][4] + bj[4]; o1.y = acc[i][5] + bj[5];
    o1.z = acc[i][6] + bj[6]; o1.w = acc[i][7] + bj[7];
    *(float4*)(Cp)     = o0;
    *(float4*)(Cp + 4) = o1;
  }
}

// ---------------- MFMA fused step v3: barrier-free, LDS-free matmul ------
// One launch per phase t: blocks 0..127 = L1 step t, 128..255 = L2 step t-1.
// Block: all 64 batches x 16 strided cols {g*512 + cg*4 + m}; wave w owns
// batches w*16..w*16+15. Both MFMA fragments load DIRECTLY from global
// (A-frag: h rows; B-frag: WP rows are fragment-contiguous). No staging.
__global__ __launch_bounds__(256)
void fused_step3(const float* __restrict__ pre,
                 const u16* __restrict__ WP1h, const u16* __restrict__ WP1l,
                 const u16* __restrict__ WP2h, const u16* __restrict__ WP2l,
                 const float* __restrict__ b2,
                 u16* __restrict__ h1hi, u16* __restrict__ h1lo,
                 u16* __restrict__ h2hi, u16* __restrict__ h2lo,
                 float* __restrict__ h2all,
                 float* __restrict__ c1, float* __restrict__ c2, int t) {
  __shared__ float ex[4][16][17];
  const int tid  = threadIdx.x;
  const int lane = tid & 63, w = tid >> 6;
  const int fr = lane & 15, f8 = (lane >> 4) * 8;
  const bool isL2 = blockIdx.x >= 128;
  const int cg = (int)(blockIdx.x & 127);

  // epilogue mapping: thread -> (batch b, local col m)
  const int b = tid >> 2, m = tid & 3;
  const int col = cg * 4 + m;
  const int ci = b * Hh + col;

  f32x4 acc = {0.f, 0.f, 0.f, 0.f};
  bool have = false;
  float p0 = 0.f, p1 = 0.f, p2 = 0.f, p3 = 0.f;

  if (!isL2) {
    if (t >= Tt) return;
    {  // prefetch pre-gate inputs (hidden under matmul)
      const float* pp = pre + ((size_t)b * Tt + t) * Gg + col;
      p0 = pp[0]; p1 = pp[512]; p2 = pp[1024]; p3 = pp[1536];
    }
    if (t > 0) {
      const int sl = (t - 1) & 1;
      const u16* Ahp = h1hi + (sl << 15) + (w * 16 + fr) * 512 + f8;
      const u16* Alp = h1lo + (sl << 15) + (w * 16 + fr) * 512 + f8;
      const u16* Bhp = WP1h + (size_t)(cg * 16 + fr) * 512 + f8;
      const u16* Blp = WP1l + (size_t)(cg * 16 + fr) * 512 + f8;
#pragma unroll
      for (int kc = 0; kc < 16; ++kc) {
        const bf16x8 ah = *(const bf16x8*)(Ahp + kc * 32);
        const bf16x8 al = *(const bf16x8*)(Alp + kc * 32);
        const bf16x8 bh = *(const bf16x8*)(Bhp + kc * 32);
        const bf16x8 bl = *(const bf16x8*)(Blp + kc * 32);
        acc = __builtin_amdgcn_mfma_f32_16x16x32_bf16(ah, bh, acc, 0, 0, 0);
        acc = __builtin_amdgcn_mfma_f32_16x16x32_bf16(ah, bl, acc, 0, 0, 0);
        acc = __builtin_amdgcn_mfma_f32_16x16x32_bf16(al, bh, acc, 0, 0, 0);
      }
      have = true;
    }
  } else {
    if (t < 1) return;
    p0 = b2[col]; p1 = b2[512 + col]; p2 = b2[1024 + col]; p3 = b2[1536 + col];
    const u16* Bhp = WP2h + (size_t)(cg * 16 + fr) * 1024 + f8;
    const u16* Blp = WP2l + (size_t)(cg * 16 + fr) * 1024 + f8;
    {  // K half 1: h1[t-1] @ W2[0:512]
      const int sl = (t - 1) & 1;
      const u16* Ahp = h1hi + (sl << 15) + (w * 16 + fr) * 512 + f8;
      const u16* Alp = h1lo + (sl << 15) + (w * 16 + fr) * 512 + f8;
#pragma unroll
      for (int kc = 0; kc < 16; ++kc) {
        const bf16x8 ah = *(const bf16x8*)(Ahp + kc * 32);
        const bf16x8 al = *(const bf16x8*)(Alp + kc * 32);
        const bf16x8 bh = *(const bf16x8*)(Bhp + kc * 32);
        const bf16x8 bl = *(const bf16x8*)(Blp + kc * 32);
        acc = __builtin_amdgcn_mfma_f32_16x16x32_bf16(ah, bh, acc, 0, 0, 0);
        acc = __builtin_amdgcn_mfma_f32_16x16x32_bf16(ah, bl, acc, 0, 0, 0);
        acc = __builtin_amdgcn_mfma_f32_16x16x32_bf16(al, bh, acc, 0, 0, 0);
      }
    }
    if (t >= 2) {  // K half 2: h2[t-2] @ W2[512:1024]
      const int sl = (t - 2) & 1;
      const u16* Ahp = h2hi + (sl << 15) + (w * 16 + fr) * 512 + f8;
      const u16* Alp = h2lo + (sl << 15) + (w * 16 + fr) * 512 + f8;
#pragma unroll
      for (int kc = 0; kc < 16; ++kc) {
        const bf16x8 ah = *(const bf16x8*)(Ahp + kc * 32);
        const bf16x8 al = *(const bf16x8*)(Alp + kc * 32);
        const bf16x8 bh = *(const bf16x8*)(Bhp + 512 + kc * 32);
        const bf16x8 bl = *(const bf16x8*)(Blp + 512 + kc * 32);
        acc = __builtin_amdgcn_mfma_f32_16x16x32_bf16(ah, bh, acc, 0, 0, 0);
        acc = __builtin_amdgcn_mfma_f32_16x16x32_bf16(ah, bl, acc, 0, 0, 0);
        acc = __builtin_amdgcn_mfma_f32_16x16x32_bf16(al, bh, acc, 0, 0, 0);
      }
    }
    have = true;
  }

  if (have) {
#pragma unroll
    for (int r = 0; r < 4; ++r)
      ex[w][(lane >> 4) * 4 + r][fr] = acc[r];
  }
  __syncthreads();

  float s0 = 0.f, s1 = 0.f, s2 = 0.f, s3 = 0.f;
  if (have) {
    s0 = ex[b >> 4][b & 15][0 + m];
    s1 = ex[b >> 4][b & 15][4 + m];
    s2 = ex[b >> 4][b & 15][8 + m];
    s3 = ex[b >> 4][b & 15][12 + m];
  }

  if (!isL2) {
    const float gi = p0 + s0, gj = p1 + s1, gf = p2 + s2, go = p3 + s3;
    const float cp = (t > 0) ? c1[ci] : 0.f;
    const float nc = fmaf(cp, sigm(gf + 1.f), sigm(gi) * tanhf(gj));
    c1[ci] = nc;
    const float nh = tanhf(nc) * sigm(go);
    u16 hh, hl;
    split_bf16(nh, hh, hl);
    const int hidx = ((t & 1) << 15) + ci;
    h1hi[hidx] = hh;
    h1lo[hidx] = hl;
  } else {
    const float gi = p0 + s0, gj = p1 + s1, gf = p2 + s2, go = p3 + s3;
    const float cp = (t >= 2) ? c2[ci] : 0.f;
    const float nc = fmaf(cp, sigm(gf + 1.f), sigm(gi) * tanhf(gj));
    c2[ci] = nc;
    const float nh = tanhf(nc) * sigm(go);
    h2all[((size_t)b * Tt + (t - 1)) * Hh + col] = nh;
    u16 hh, hl;
    split_bf16(nh, hh, hl);
    const int hidx = (((t - 1) & 1) << 15) + ci;
    h2hi[hidx] = hh;
    h2lo[hidx] = hl;
  }
}

// ---------------- Output projection + softmax + CE ----------------
__global__ __launch_bounds__(128)
void proj_softmax(const float* __restrict__ h2, const float* __restrict__ Wout,
                  const float* __restrict__ bout, const int* __restrict__ labels,
                  float* __restrict__ preds, float* __restrict__ ce) {
  __shared__ float hs[8][Hh];
  __shared__ float wred[2][2];
  const int tid = threadIdx.x;
  const int wid = tid >> 6;
  const int r0  = blockIdx.x * 8;

  for (int i = tid; i < 8 * (Hh / 4); i += 128) {
    const int row = i >> 7;
    const int c4  = i & 127;
    ((float4*)hs[row])[c4] =
        ((const float4*)(h2 + ((size_t)(r0 + row) * Hh)))[c4];
  }
  __syncthreads();

  const bool act = (tid < Cc);
  float acc[8];
  {
    const float bj = act ? bout[tid] : 0.f;
#pragma unroll
    for (int i = 0; i < 8; ++i) acc[i] = bj;
  }
  if (act) {
#pragma unroll 4
    for (int k = 0; k < Hh; ++k) {
      const float w = Wout[k * Cc + tid];
#pragma unroll
      for (int i = 0; i < 8; ++i) acc[i] = fmaf(hs[i][k], w, acc[i]);
    }
  }

  for (int row = 0; row < 8; ++row) {
    const float v = act ? acc[row] : -INFINITY;
    float mw = v;
#pragma unroll
    for (int off = 32; off > 0; off >>= 1) mw = fmaxf(mw, __shfl_xor(mw, off));
    if ((tid & 63) == 0) wred[0][wid] = mw;
    __syncthreads();
    const float mx = fmaxf(wred[0][0], wred[0][1]);
    const float e = act ? expf(v - mx) : 0.f;
    float sw = e;
#pragma unroll
    for (int off = 32; off > 0; off >>= 1) sw += __shfl_xor(sw, off);
    if ((tid & 63) == 0) wred[1][wid] = sw;
    __syncthreads();
    const float sum = wred[1][0] + wred[1][1];
    if (act) preds[(size_t)(r0 + row) * Cc + tid] = e / sum;
    const int lab = labels[r0 + row];
    if (tid == lab) ce[r0 + row] = logf(sum) + mx - v;
    __syncthreads();
  }
}

__global__ __launch_bounds__(256)
void reduce_cost(const float* __restrict__ ce, float* __restrict__ out) {
  __shared__ float red[256];
  const int tid = threadIdx.x;
  float s = 0.f;
  for (int i = tid; i < ROWS; i += 256) s += ce[i];
  red[tid] = s;
  __syncthreads();
  for (int st = 128; st > 0; st >>= 1) {
    if (tid < st) red[tid] += red[tid + st];
    __syncthreads();
  }
  if (tid == 0) out[0] = red[0] / (float)Bb;
}

// ---------------- launch ----------------
extern "C" void kernel_launch(void* const* d_in, const int* in_sizes, int n_in,
                              void* d_out, int out_size, void* d_ws, size_t ws_size,
                              hipStream_t stream) {
  const float* inputs = (const float*)d_in[0];
  const int*   labels = (const int*)d_in[1];
  const float* W1     = (const float*)d_in[2];
  const float* b1     = (const float*)d_in[3];
  const float* W2     = (const float*)d_in[4];
  const float* b2     = (const float*)d_in[5];
  const float* Wout   = (const float*)d_in[6];
  const float* bout   = (const float*)d_in[7];
  float* out = (float*)d_out;

  float* ws    = (float*)d_ws;
  float* pre   = ws;                               // ROWS*Gg   (16M f32)
  float* h2all = pre   + (size_t)ROWS * Gg;        // ROWS*Hh   (4M)
  float* c1    = h2all + (size_t)ROWS * Hh;        // 64*512
  float* c2    = c1    + (size_t)Bb * Hh;
  float* ceb   = c2    + (size_t)Bb * Hh;          // ROWS
  u16* h1hi = (u16*)(ceb + ROWS);                  // [2][64][512]
  u16* h1lo = h1hi + 2 * 64 * 512;
  u16* h2hi = h1lo + 2 * 64 * 512;
  u16* h2lo = h2hi + 2 * 64 * 512;
  u16* WP1h = h2lo + 2 * 64 * 512;                 // 128*16*512
  u16* WP1l = WP1h + 128 * 16 * 512;
  u16* WP2h = WP1l + 128 * 16 * 512;               // 128*16*1024
  u16* WP2l = WP2h + 128 * 16 * 1024;
  u16* Xhi  = WP2l + 128 * 16 * 1024;              // ROWS*Dd
  u16* Xlo  = Xhi  + (size_t)ROWS * Dd;
  u16* W1Th = Xlo  + (size_t)ROWS * Dd;            // Gg*Dd
  u16* W1Tl = W1Th + (size_t)Gg * Dd;
  const size_t need = (size_t)((char*)(W1Tl + (size_t)Gg * Dd) - (char*)d_ws);
  const bool use_mfma = ws_size >= need;

  // recurrent weights: permute+split once
  permuteW<<<dim3(16, 64), dim3(32, 8), 0, stream>>>(
      W1 + (size_t)Dd * Gg, WP1h, WP1l, 512);
  permuteW<<<dim3(32, 64), dim3(32, 8), 0, stream>>>(W2, WP2h, WP2l, 1024);

  // Layer 1 input projection: pre = X @ W1[0:D,:] + b1
  if (use_mfma) {
    convert_hilo<<<2048, 256, 0, stream>>>(inputs, Xhi, Xlo, ROWS * Dd / 4);
    convertT_w1<<<dim3(64, 64), dim3(32, 8), 0, stream>>>(W1, W1Th, W1Tl);
    gemm1_mfma<<<dim3(Gg / 128, ROWS / 128), 256, 0, stream>>>(
        Xhi, Xlo, W1Th, W1Tl, b1, pre);
  } else {
    sgemm_bias<<<dim3(Gg / BN, ROWS / BM), dim3(256), 0, stream>>>(
        inputs, W1, b1, pre, ROWS, Gg, Dd);
  }

  // Recurrence: phase t = L1 step t (blocks 0..127) + L2 step t-1 (128..255)
  for (int t = 0; t <= Tt; ++t)
    fused_step3<<<256, 256, 0, stream>>>(pre, WP1h, WP1l, WP2h, WP2l, b2,
                                         h1hi, h1lo, h2hi, h2lo,
                                         h2all, c1, c2, t);

  proj_softmax<<<ROWS / 8, 128, 0, stream>>>(h2all, Wout, bout, labels, out, ceb);
  reduce_cost<<<1, 256, 0, stream>>>(ceb, out + (size_t)ROWS * Cc);
}